// Round 5
// baseline (1194.719 us; speedup 1.0000x reference)
//
#include <hip/hip_runtime.h>
#include <hip/hip_bf16.h>
#include <math.h>

#define Hh 48
#define Ww 160
#define NP 7680      // H*W
#define NCHUNK 32
#define CHSZ (NP / NCHUNK) // 240

using bf16 = __hip_bfloat16;

__device__ __forceinline__ float bfdec(unsigned short u) {
  return __uint_as_float(((unsigned)u) << 16);
}
__device__ __forceinline__ float ldany(const void* p, size_t i, int isbf) {
  return isbf ? bfdec(((const unsigned short*)p)[i]) : ((const float*)p)[i];
}

__device__ __forceinline__ int mapidx(int i, int n, int mode) {
  if (mode == 0) return i < 0 ? 0 : (i >= n ? n - 1 : i);       // edge
  return i < 0 ? -i : (i >= n ? 2 * n - 2 - i : i);             // reflect
}

__device__ __forceinline__ float act_apply(float v, int act) {
  if (act == 1) return v > 0.f ? v : expm1f(v);                  // elu
  if (act == 2) {                                                // gelu (tanh approx)
    float c = v + 0.044715f * v * v * v;
    return 0.5f * v * (1.f + tanhf(0.7978845608028654f * c));
  }
  return v;
}

// ---------------- dtype sniffer ----------------
__global__ __launch_bounds__(256) void sniff_k(const unsigned short* __restrict__ w,
                                               int* __restrict__ flag) {
  __shared__ int cnt[256];
  int c = 0;
  for (int i = threadIdx.x; i < 2048; i += 256) {
    float a = fabsf(bfdec(w[i]));
    if (a > 1e-3f && a < 0.5f) c++;
  }
  cnt[threadIdx.x] = c;
  __syncthreads();
  for (int s = 128; s > 0; s >>= 1) {
    if (threadIdx.x < s) cnt[threadIdx.x] += cnt[threadIdx.x + s];
    __syncthreads();
  }
  if (threadIdx.x == 0) flag[0] = (cnt[0] > 1536) ? 1 : 0;
}

// ---------------- merged prep: cvt + repacks + bias, one launch ----------------
__global__ __launch_bounds__(256) void prep_k(const int* __restrict__ flag,
    const void* disp, const void* invK, const void* K, const void* rw2,
    const void* rb2, const void* sw2, const void* sb2, const void* ow2, const void* ob2,
    const void* rb1, const void* sb1, const void* ob1, const void* fb1, const void* fb2,
    const void* frb, const void* fl_w1, const void* fl_w2, const void* fr_w,
    const void* rot_w1, const void* scl_w1, const void* opa_w1,
    float* __restrict__ dispf, float* __restrict__ smallf, float* __restrict__ biasf,
    float* __restrict__ wp_fl1, float* __restrict__ wp_fl2, float* __restrict__ wp_fr,
    float* __restrict__ wp_h1) {
  int i = blockIdx.x * 256 + threadIdx.x;
  int f = *flag;
  if (i < 7680) { dispf[i] = ldany(disp, i, f); return; }
  i -= 7680;
  if (i < 508) {
    const void* src; int off;
    if (i < 16)       { src = invK; off = i; }
    else if (i < 32)  { src = K;    off = i - 16; }
    else if (i < 320) { src = rw2;  off = i - 32; }
    else if (i < 324) { src = rb2;  off = i - 320; }
    else if (i < 486) { src = sw2;  off = i - 324; }
    else if (i < 489) { src = sb2;  off = i - 486; }
    else if (i < 507) { src = ow2;  off = i - 489; }
    else              { src = ob2;  off = i - 507; }
    smallf[i] = ldany(src, off, f); return;
  }
  i -= 508;
  if (i < 336) {
    if (i < 8) biasf[i] = ldany(rb1, i, f);
    else if (i < 14) biasf[i] = ldany(sb1, i - 8, f);
    else if (i < 16) biasf[i] = ldany(ob1, i - 14, f);
    else if (i < 144) biasf[i] = ldany(fb1, i - 16, f);
    else if (i < 208) biasf[i] = ldany(fb2, i - 144, f);
    else biasf[i] = ldany(frb, i - 208, f);
    return;
  }
  i -= 336;
  if (i < 147456) { int co = i / 1152, rem = i - co * 1152;
    wp_fl1[(size_t)rem * 128 + co] = ldany(fl_w1, i, f); return; }
  i -= 147456;
  if (i < 73728) { int co = i / 1152, rem = i - co * 1152;
    wp_fl2[(size_t)rem * 64 + co] = ldany(fl_w2, i, f); return; }
  i -= 73728;
  if (i < 73728) { int co = i / 576, rem = i - co * 576;
    wp_fr[(size_t)rem * 128 + co] = ldany(fr_w, i, f); return; }
  i -= 73728;
  if (i < 9216) { int co = i / 1152, rem = i - co * 1152;
    wp_h1[(size_t)rem * 16 + co] = ldany(rot_w1, i, f); return; }
  i -= 9216;
  if (i < 6912) { int co = i / 1152, rem = i - co * 1152;
    wp_h1[(size_t)rem * 16 + 8 + co] = ldany(scl_w1, i, f); return; }
  i -= 6912;
  if (i < 2304) { int co = i / 1152, rem = i - co * 1152;
    wp_h1[(size_t)rem * 16 + 14 + co] = ldany(opa_w1, i, f); return; }
}

// ---------------- scalar-weight direct 3x3 conv ----------------
// lane = pixel: tile 2 rows x 32 cols; block 256 = 4 waves; wave owns COW couts.
// x layout [Cin][H][W] (bf16 or f32 per flag if FIRST); weights [ci*9+k][Cout].
// grid (Ww/32=5, Hh/2=24, Cout/(4*COW))
template<bool FIRST, bool FINAL, int COW>
__global__ __launch_bounds__(256) void conv_s_k(const void* __restrict__ xv,
    const float* __restrict__ wp, const float* __restrict__ bias, void* __restrict__ out,
    const int* __restrict__ flag, int Cin, int Cout, int padmode, int act) {
  const int lane = threadIdx.x & 63, wave = threadIdx.x >> 6;
  const int hl = lane >> 5, wl = lane & 31;
  const int h = blockIdx.y * 2 + hl, w = blockIdx.x * 32 + wl;
  const int coB = (blockIdx.z * 4 + wave) * COW;
  const int isbf = FIRST ? *flag : 0;
  int off9[9];
#pragma unroll
  for (int r = 0; r < 3; r++) {
    int rr = mapidx(h + r - 1, Hh, padmode);
#pragma unroll
    for (int s = 0; s < 3; s++)
      off9[r * 3 + s] = rr * Ww + mapidx(w + s - 1, Ww, padmode);
  }
  float acc[COW];
#pragma unroll
  for (int c = 0; c < COW; c++) acc[c] = 0.f;
  for (int ci = 0; ci < Cin; ci++) {
    float xr[9];
    size_t xb = (size_t)ci * (Hh * Ww);
#pragma unroll
    for (int k = 0; k < 9; k++) xr[k] = ldany(xv, xb + off9[k], isbf);
    const float* wb = wp + (size_t)ci * 9 * Cout + coB;
#pragma unroll
    for (int k = 0; k < 9; k++)
#pragma unroll
      for (int c = 0; c < COW; c++)
        acc[c] = fmaf(xr[k], wb[(size_t)k * Cout + c], acc[c]);
  }
  const int obf = FINAL ? *flag : 0;
#pragma unroll
  for (int c = 0; c < COW; c++) {
    float v = act_apply(acc[c] + bias[coB + c], act);
    size_t oi = ((size_t)(coB + c) * Hh + h) * Ww + w;
    if (FINAL && obf) ((bf16*)out)[oi] = __float2bfloat16(v);
    else ((float*)out)[oi] = v;
  }
}

// ---------------- head2 + per-gaussian prep ----------------
__global__ __launch_bounds__(128) void head2_prep_k(const float* __restrict__ h1,
    const float* __restrict__ smallf, const float* __restrict__ dispf,
    float* __restrict__ params, float* __restrict__ zbuf, int* __restrict__ rank) {
  const float* invK = smallf;
  const float* Km   = smallf + 16;
  const float* rw2  = smallf + 32;
  const float* rb2  = smallf + 320;
  const float* sw2  = smallf + 324;
  const float* sb2  = smallf + 486;
  const float* ow2  = smallf + 489;
  const float* ob2  = smallf + 507;
  int p = blockIdx.x * 128 + threadIdx.x;
  if (p >= NP) return;
  int hh = p / Ww, ww = p - hh * Ww;
  float racc[4], sacc[3], oacc;
#pragma unroll
  for (int i = 0; i < 4; i++) racc[i] = rb2[i];
#pragma unroll
  for (int i = 0; i < 3; i++) sacc[i] = sb2[i];
  oacc = ob2[0];
  for (int ci = 0; ci < 16; ci++) {
    float t9[9];
#pragma unroll
    for (int r = 0; r < 3; r++) {
      int rr = mapidx(hh + r - 1, Hh, 0);
#pragma unroll
      for (int s = 0; s < 3; s++) {
        int cc = mapidx(ww + s - 1, Ww, 0);
        t9[r * 3 + s] = h1[(size_t)ci * NP + rr * Ww + cc];
      }
    }
    if (ci < 8) {
      for (int co = 0; co < 4; co++)
#pragma unroll
        for (int k = 0; k < 9; k++)
          racc[co] = fmaf(t9[k], rw2[(co * 8 + ci) * 9 + k], racc[co]);
    } else if (ci < 14) {
      int c2 = ci - 8;
      for (int co = 0; co < 3; co++)
#pragma unroll
        for (int k = 0; k < 9; k++)
          sacc[co] = fmaf(t9[k], sw2[(co * 6 + c2) * 9 + k], sacc[co]);
    } else {
      int c2 = ci - 14;
#pragma unroll
      for (int k = 0; k < 9; k++)
        oacc = fmaf(t9[k], ow2[c2 * 9 + k], oacc);
    }
  }
  float nq = sqrtf(racc[0]*racc[0] + racc[1]*racc[1] + racc[2]*racc[2] + racc[3]*racc[3]);
  nq = fmaxf(nq, 1e-12f);
  float qw = racc[0] / nq, qx = racc[1] / nq, qy = racc[2] / nq, qz = racc[3] / nq;
  float s0 = fabsf(sacc[0]), s1 = fabsf(sacc[1]), s2 = fabsf(sacc[2]);
  float opa = 1.f / (1.f + __expf(-oacc));
  float d = dispf[p];
  float scaled = 0.01f + 9.99f * d;
  float depth = fminf(fmaxf(1.f / scaled, 0.1f), 100.f);
  float M00 = invK[0], M01 = invK[1], M02 = invK[2];
  float M10 = invK[4], M11 = invK[5], M12 = invK[6];
  float M20 = invK[8], M21 = invK[9], M22 = invK[10];
  float gxf = (float)ww, gyf = (float)hh;
  float X = (M00 * gxf + M01 * gyf + M02) * depth;
  float Y = (M10 * gxf + M11 * gyf + M12) * depth;
  float Z = (M20 * gxf + M21 * gyf + M22) * depth;
  float fxk = Km[0], fyk = Km[5];
  float cxk = Km[2], cyk = Km[6];
  float u = fxk * X / Z + cxk;
  float v = fyk * Y / Z + cyk;
  float R00 = 1.f - 2.f*(qy*qy + qz*qz), R01 = 2.f*(qx*qy - qw*qz), R02 = 2.f*(qx*qz + qw*qy);
  float R10 = 2.f*(qx*qy + qw*qz), R11 = 1.f - 2.f*(qx*qx + qz*qz), R12 = 2.f*(qy*qz - qw*qx);
  float R20 = 2.f*(qx*qz - qw*qy), R21 = 2.f*(qy*qz + qw*qx), R22 = 1.f - 2.f*(qx*qx + qy*qy);
  float M0a = R00*s0, M0b = R01*s1, M0c = R02*s2;
  float M1a = R10*s0, M1b = R11*s1, M1c = R12*s2;
  float M2a = R20*s0, M2b = R21*s1, M2c = R22*s2;
  float S00 = M0a*M0a + M0b*M0b + M0c*M0c;
  float S01 = M0a*M1a + M0b*M1b + M0c*M1c;
  float S02 = M0a*M2a + M0b*M2b + M0c*M2c;
  float S11 = M1a*M1a + M1b*M1b + M1c*M1c;
  float S12 = M1a*M2a + M1b*M2b + M1c*M2c;
  float S22 = M2a*M2a + M2b*M2b + M2c*M2c;
  float iz = 1.f / Z;
  float j00 = fxk * iz, j02 = -fxk * X * iz * iz;
  float j11 = fyk * iz, j12 = -fyk * Y * iz * iz;
  float c00 = j00*j00*S00 + 2.f*j00*j02*S02 + j02*j02*S22 + 0.3f;
  float c01 = j00*j11*S01 + j00*j12*S02 + j02*j11*S12 + j02*j12*S22;
  float c11 = j11*j11*S11 + 2.f*j11*j12*S12 + j12*j12*S22 + 0.3f;
  float det = c00 * c11 - c01 * c01;
  float idet = 1.f / det;
  float* pr = params + (size_t)p * 8;
  pr[0] = u; pr[1] = v; pr[2] = c11 * idet; pr[3] = -c01 * idet;
  pr[4] = c00 * idet; pr[5] = opa; pr[6] = Z; pr[7] = 0.f;
  zbuf[p] = Z;
  rank[p] = 0;
}

// ---------------- rank-by-count stable argsort (z ascending, idx tiebreak) ----------------
// grid (NP/256, 8 slices); each block counts its slice, atomicAdd into rank[i]
__global__ __launch_bounds__(256) void rank_count_k(const float* __restrict__ zbuf,
                                                    int* __restrict__ rank) {
  int i = blockIdx.x * 256 + threadIdx.x;
  int sid = blockIdx.y;
  float zi = zbuf[i];
  const float4* zv = (const float4*)(zbuf + sid * 960);
  int cnt = 0;
  for (int t = 0; t < 240; t++) {
    float4 z4 = zv[t];
    int jb = sid * 960 + t * 4;
    cnt += (z4.x < zi || (z4.x == zi && jb + 0 < i)) ? 1 : 0;
    cnt += (z4.y < zi || (z4.y == zi && jb + 1 < i)) ? 1 : 0;
    cnt += (z4.z < zi || (z4.z == zi && jb + 2 < i)) ? 1 : 0;
    cnt += (z4.w < zi || (z4.w == zi && jb + 3 < i)) ? 1 : 0;
  }
  atomicAdd(&rank[i], cnt);
}

__global__ __launch_bounds__(256) void scatter_k(const int* __restrict__ rank,
                                                 int* __restrict__ ord) {
  int i = blockIdx.x * 256 + threadIdx.x;
  ord[rank[i]] = i;
}

// ---------------- gather into sorted order + zero lev ----------------
__global__ __launch_bounds__(256) void gather_k(const int* __restrict__ ord,
    const float* __restrict__ params, const float* __restrict__ t2,
    float* __restrict__ params_s, float* __restrict__ feat_s, float* __restrict__ lev) {
  int gid = blockIdx.x * 256 + threadIdx.x;   // NP*64
  int n = gid >> 6, c = gid & 63;
  int orig = ord[n];
  feat_s[gid] = t2[(size_t)c * NP + orig];
  lev[gid] = 0.f;
  if (c < 8) params_s[(n << 3) + c] = params[((size_t)orig << 3) + c];
}

// ---------------- pass A: per-chunk transmittance ----------------
// grid (NP/256, NCHUNK), block 256
__global__ __launch_bounds__(256) void alpha_k(const float* __restrict__ params_s,
    float* __restrict__ tch) {
  const int p = blockIdx.x * 256 + threadIdx.x;
  const int ch = blockIdx.y;
  const float px = (float)(p % Ww), py = (float)(p / Ww);
  float T = 1.f;
  const float4* pv = (const float4*)params_s + (size_t)ch * CHSZ * 2;
  for (int n0 = 0; n0 < CHSZ; n0 += 4) {
    float4 pa[4], pb[4];
#pragma unroll
    for (int u = 0; u < 4; u++) { pa[u] = pv[(n0 + u) * 2]; pb[u] = pv[(n0 + u) * 2 + 1]; }
#pragma unroll
    for (int u = 0; u < 4; u++) {
      float dx = px - pa[u].x, dy = py - pa[u].y;
      float power = -0.5f * (pa[u].z * dx * dx + pb[u].x * dy * dy) - pa[u].w * dx * dy;
      if (__any(power > -18.f)) {   // alpha<1.6e-8: T*(1-a) rounds to T in fp32
        float al = fminf(pb[u].y * __expf(power), 0.99f);
        T *= 1.f - al;
      }
    }
  }
  tch[(size_t)ch * NP + p] = T;
}

// ---------------- pass B: features, seeded by prefix transmittance ----------------
// grid (NP/128, NCHUNK), block 128; one wave owns all 64 feats of its 64 px
__global__ __launch_bounds__(128) void raster_k(const float* __restrict__ params_s,
    const float* __restrict__ feat_s, const float* __restrict__ tch,
    float* __restrict__ lev) {
  const int p = blockIdx.x * 128 + threadIdx.x;
  const int ch = blockIdx.y;
  float Ts = 1.f;
  for (int c = 0; c < ch; c++) Ts *= tch[(size_t)c * NP + p];
  const float px = (float)(p % Ww), py = (float)(p / Ww);
  float4 acc[16];
#pragma unroll
  for (int q = 0; q < 16; q++) acc[q] = make_float4(0.f, 0.f, 0.f, 0.f);
  float T = 1.f;
  const int g0 = ch * CHSZ;
  const float4* pv = (const float4*)params_s + (size_t)g0 * 2;
  for (int n0 = 0; n0 < CHSZ; n0 += 4) {
    float4 pa[4], pb[4];
#pragma unroll
    for (int u = 0; u < 4; u++) { pa[u] = pv[(n0 + u) * 2]; pb[u] = pv[(n0 + u) * 2 + 1]; }
#pragma unroll
    for (int u = 0; u < 4; u++) {
      float dx = px - pa[u].x, dy = py - pa[u].y;
      float power = -0.5f * (pa[u].z * dx * dx + pb[u].x * dy * dy) - pa[u].w * dx * dy;
      if (__any(power > -18.f)) {
        float al = fminf(pb[u].y * __expf(power), 0.99f);
        float wgt = al * T;
        T *= 1.f - al;
        if (__any(wgt > 0.f)) {
          const float4* fr = (const float4*)(feat_s + (((size_t)(g0 + n0 + u)) << 6));
#pragma unroll
          for (int q = 0; q < 16; q++) {
            float4 f = fr[q];
            acc[q].x = fmaf(wgt, f.x, acc[q].x);
            acc[q].y = fmaf(wgt, f.y, acc[q].y);
            acc[q].z = fmaf(wgt, f.z, acc[q].z);
            acc[q].w = fmaf(wgt, f.w, acc[q].w);
          }
        }
      }
    }
  }
#pragma unroll
  for (int q = 0; q < 16; q++) {
    atomicAdd(&lev[(size_t)(q * 4 + 0) * NP + p], Ts * acc[q].x);
    atomicAdd(&lev[(size_t)(q * 4 + 1) * NP + p], Ts * acc[q].y);
    atomicAdd(&lev[(size_t)(q * 4 + 2) * NP + p], Ts * acc[q].z);
    atomicAdd(&lev[(size_t)(q * 4 + 3) * NP + p], Ts * acc[q].w);
  }
}

extern "C" void kernel_launch(void* const* d_in, const int* in_sizes, int n_in,
                              void* d_out, int out_size, void* d_ws, size_t ws_size,
                              hipStream_t stream) {
  (void)in_sizes; (void)n_in; (void)out_size; (void)ws_size;
  const void* init_feature = d_in[0];
  const void* disp   = d_in[1];
  const void* invK   = d_in[2];
  const void* Km     = d_in[3];
  const void* rot_w1 = d_in[4];
  const void* rot_b1 = d_in[5];
  const void* rot_w2 = d_in[6];
  const void* rot_b2 = d_in[7];
  const void* scl_w1 = d_in[8];
  const void* scl_b1 = d_in[9];
  const void* scl_w2 = d_in[10];
  const void* scl_b2 = d_in[11];
  const void* opa_w1 = d_in[12];
  const void* opa_b1 = d_in[13];
  const void* opa_w2 = d_in[14];
  const void* opa_b2 = d_in[15];
  const void* fl_w1  = d_in[16];
  const void* fl_b1  = d_in[17];
  const void* fl_w2  = d_in[18];
  const void* fl_b2  = d_in[19];
  const void* fr_w   = d_in[20];
  const void* fr_b   = d_in[21];

  float* wsf = (float*)d_ws;
  // layout (floats); total 3,294,224 f = 13.18 MB (< 16.6 MB proven in R1)
  int*   flag    = (int*)wsf;                   // @0        16
  float* smallf  = wsf + 16;                    // 512
  float* dispf   = wsf + 528;                   // 7680
  float* biasf   = wsf + 8208;                  // 512
  float* wp_h1   = wsf + 8720;                  // 18432
  float* wp_fl1  = wsf + 27152;                 // 147456
  float* wp_fl2  = wsf + 174608;                // 73728
  float* wp_fr   = wsf + 248336;                // 73728
  float* params_s= wsf + 322064;                // 61440
  float* feat_s  = wsf + 383504;                // 491520
  float* tch     = wsf + 875024;                // 32*7680 = 245760
  float* lev     = wsf + 1120784;               // 491520
  float* t1      = wsf + 1612304;               // 983040
  float* h1      = wsf + 2595344;               // 122880
  float* t2      = wsf + 2718224;               // 491520
  float* params  = wsf + 3209744;               // 61440
  float* zbuf    = wsf + 3271184;               // 7680
  int*   rank    = (int*)(wsf + 3278864);       // 7680
  int*   ord     = (int*)(wsf + 3286544);       // 7680

  // dtype sniff, then one merged prep launch
  sniff_k<<<1, 256, 0, stream>>>((const unsigned short*)fl_w1, flag);
  prep_k<<<1258, 256, 0, stream>>>(flag,
      disp, invK, Km, rot_w2, rot_b2, scl_w2, scl_b2, opa_w2, opa_b2,
      rot_b1, scl_b1, opa_b1, fl_b1, fl_b2, fr_b,
      fl_w1, fl_w2, fr_w, rot_w1, scl_w1, opa_w1,
      dispf, smallf, biasf, wp_fl1, wp_fl2, wp_fr, wp_h1);

  // heads first conv (16 ch, edge, gelu): COW=4, z=1
  conv_s_k<true, false, 4><<<dim3(5, 24, 1), 256, 0, stream>>>(
      init_feature, wp_h1, biasf, h1, flag, 128, 16, 0, 2);
  // gs_feat chain (reflect, elu): fl1 COW=8 z=4, fl2 COW=8 z=2
  conv_s_k<true, false, 8><<<dim3(5, 24, 4), 256, 0, stream>>>(
      init_feature, wp_fl1, biasf + 16, t1, flag, 128, 128, 1, 1);
  conv_s_k<false, false, 8><<<dim3(5, 24, 2), 256, 0, stream>>>(
      t1, wp_fl2, biasf + 144, t2, flag, 128, 64, 1, 1);
  // heads second conv + gaussian prep (+ zbuf, rank=0)
  head2_prep_k<<<60, 128, 0, stream>>>(h1, smallf, dispf, params, zbuf, rank);
  // stable argsort by z via rank-count, then scatter + gather (+ zero lev)
  rank_count_k<<<dim3(30, 8), 256, 0, stream>>>(zbuf, rank);
  scatter_k<<<30, 256, 0, stream>>>(rank, ord);
  gather_k<<<(NP * 64) / 256, 256, 0, stream>>>(ord, params, t2, params_s, feat_s, lev);
  // two-pass raster: chunk transmittances, then features + atomic combine
  alpha_k<<<dim3(NP / 256, NCHUNK), 256, 0, stream>>>(params_s, tch);
  raster_k<<<dim3(NP / 128, NCHUNK), 128, 0, stream>>>(params_s, feat_s, tch, lev);
  // final conv (reflect, elu) -> out (dtype per flag): COW=16, z=2
  conv_s_k<false, true, 16><<<dim3(5, 24, 2), 256, 0, stream>>>(
      lev, wp_fr, biasf + 208, d_out, flag, 64, 128, 1, 1);
}

// Round 6
// 821.690 us; speedup vs baseline: 1.4540x; 1.4540x over previous
//
#include <hip/hip_runtime.h>
#include <hip/hip_bf16.h>
#include <math.h>

#define Hh 48
#define Ww 160
#define NP 7680      // H*W
#define NCHUNK 32
#define CHSZ (NP / NCHUNK) // 240

using bf16 = __hip_bfloat16;

__device__ __forceinline__ float bfdec(unsigned short u) {
  return __uint_as_float(((unsigned)u) << 16);
}
__device__ __forceinline__ float ldany(const void* p, size_t i, int isbf) {
  return isbf ? bfdec(((const unsigned short*)p)[i]) : ((const float*)p)[i];
}

__device__ __forceinline__ int mapidx(int i, int n, int mode) {
  if (mode == 0) return i < 0 ? 0 : (i >= n ? n - 1 : i);       // edge
  return i < 0 ? -i : (i >= n ? 2 * n - 2 - i : i);             // reflect
}

__device__ __forceinline__ float act_apply(float v, int act) {
  if (act == 1) return v > 0.f ? v : expm1f(v);                  // elu
  if (act == 2) {                                                // gelu (tanh approx)
    float c = v + 0.044715f * v * v * v;
    return 0.5f * v * (1.f + tanhf(0.7978845608028654f * c));
  }
  return v;
}

// ---------------- dtype sniffer ----------------
__global__ __launch_bounds__(256) void sniff_k(const unsigned short* __restrict__ w,
                                               int* __restrict__ flag) {
  __shared__ int cnt[256];
  int c = 0;
  for (int i = threadIdx.x; i < 2048; i += 256) {
    float a = fabsf(bfdec(w[i]));
    if (a > 1e-3f && a < 0.5f) c++;
  }
  cnt[threadIdx.x] = c;
  __syncthreads();
  for (int s = 128; s > 0; s >>= 1) {
    if (threadIdx.x < s) cnt[threadIdx.x] += cnt[threadIdx.x + s];
    __syncthreads();
  }
  if (threadIdx.x == 0) flag[0] = (cnt[0] > 1536) ? 1 : 0;
}

// ---------------- merged prep: cvt + repacks + bias + zero-init, one launch ----------------
// segments: disp 7680 | small 508 | bias 336 | fl1 147456 | fl2 73728 | fr 73728
//           | rot1 9216 | scl1 6912 | opa1 2304 | zero t1r 983040 | zero t2r 491520
__global__ __launch_bounds__(256) void prep_k(const int* __restrict__ flag,
    const void* disp, const void* invK, const void* K, const void* rw2,
    const void* rb2, const void* sw2, const void* sb2, const void* ow2, const void* ob2,
    const void* rb1, const void* sb1, const void* ob1, const void* fb1, const void* fb2,
    const void* frb, const void* fl_w1, const void* fl_w2, const void* fr_w,
    const void* rot_w1, const void* scl_w1, const void* opa_w1,
    float* __restrict__ dispf, float* __restrict__ smallf, float* __restrict__ biasf,
    float* __restrict__ wp_fl1, float* __restrict__ wp_fl2, float* __restrict__ wp_fr,
    float* __restrict__ wp_h1, float* __restrict__ t1r, float* __restrict__ t2r) {
  int i = blockIdx.x * 256 + threadIdx.x;
  int f = *flag;
  if (i < 7680) { dispf[i] = ldany(disp, i, f); return; }
  i -= 7680;
  if (i < 508) {
    const void* src; int off;
    if (i < 16)       { src = invK; off = i; }
    else if (i < 32)  { src = K;    off = i - 16; }
    else if (i < 320) { src = rw2;  off = i - 32; }
    else if (i < 324) { src = rb2;  off = i - 320; }
    else if (i < 486) { src = sw2;  off = i - 324; }
    else if (i < 489) { src = sb2;  off = i - 486; }
    else if (i < 507) { src = ow2;  off = i - 489; }
    else              { src = ob2;  off = i - 507; }
    smallf[i] = ldany(src, off, f); return;
  }
  i -= 508;
  if (i < 336) {
    if (i < 8) biasf[i] = ldany(rb1, i, f);
    else if (i < 14) biasf[i] = ldany(sb1, i - 8, f);
    else if (i < 16) biasf[i] = ldany(ob1, i - 14, f);
    else if (i < 144) biasf[i] = ldany(fb1, i - 16, f);
    else if (i < 208) biasf[i] = ldany(fb2, i - 144, f);
    else biasf[i] = ldany(frb, i - 208, f);
    return;
  }
  i -= 336;
  if (i < 147456) { int co = i / 1152, rem = i - co * 1152;
    wp_fl1[(size_t)rem * 128 + co] = ldany(fl_w1, i, f); return; }
  i -= 147456;
  if (i < 73728) { int co = i / 1152, rem = i - co * 1152;
    wp_fl2[(size_t)rem * 64 + co] = ldany(fl_w2, i, f); return; }
  i -= 73728;
  if (i < 73728) { int co = i / 576, rem = i - co * 576;
    wp_fr[(size_t)rem * 128 + co] = ldany(fr_w, i, f); return; }
  i -= 73728;
  if (i < 9216) { int co = i / 1152, rem = i - co * 1152;
    wp_h1[(size_t)rem * 16 + co] = ldany(rot_w1, i, f); return; }
  i -= 9216;
  if (i < 6912) { int co = i / 1152, rem = i - co * 1152;
    wp_h1[(size_t)rem * 16 + 8 + co] = ldany(scl_w1, i, f); return; }
  i -= 6912;
  if (i < 2304) { int co = i / 1152, rem = i - co * 1152;
    wp_h1[(size_t)rem * 16 + 14 + co] = ldany(opa_w1, i, f); return; }
  i -= 2304;
  if (i < 983040) { t1r[i] = 0.f; return; }
  i -= 983040;
  if (i < 491520) { t2r[i] = 0.f; return; }
}

// ---------------- tiled direct 3x3 conv (LDS-staged, Cin/Cout-splittable) ----------------
// block 256 = COB couts x (256/COB) w-groups of PXT px; tile = 32 w, 1 h
// weights [ci*9+k][Cout]; grid (5, 48, co_nblk * nci_chunks)
// ACTIN: staged input gets elu(x + bias_in[ci]); ATOMIC: epilogue atomicAdds raw sums.
template<bool FIRST, bool FINAL, int COB, int PXT, bool ACTIN, bool ATOMIC>
__global__ __launch_bounds__(256) void conv_tiled_k(const void* __restrict__ xv,
    const float* __restrict__ wp, const float* __restrict__ bias,
    const float* __restrict__ bias_in, void* __restrict__ out,
    const int* __restrict__ flag, int Cout, int padmode, int act,
    int co_nblk, int ci_chunk) {
  __shared__ float sx[8][3][36];
  const int h = blockIdx.y;
  const int w0 = blockIdx.x * 32;
  const int coL = threadIdx.x & (COB - 1);
  const int co = (blockIdx.z % co_nblk) * COB + coL;
  const int ci_begin = (blockIdx.z / co_nblk) * ci_chunk;
  const int wg = threadIdx.x / COB;
  const int wl = wg * PXT;
  const int isbf = FIRST ? *flag : 0;
  float acc[PXT];
#pragma unroll
  for (int i = 0; i < PXT; i++) acc[i] = 0.f;
  int rows[3];
#pragma unroll
  for (int r = 0; r < 3; r++) rows[r] = mapidx(h + r - 1, Hh, padmode);
  for (int ci0 = ci_begin; ci0 < ci_begin + ci_chunk; ci0 += 8) {
    __syncthreads();
    for (int idx = threadIdx.x; idx < 816; idx += 256) {
      int ci = idx / 102; int rem = idx - ci * 102;
      int r = rem / 34;   int wi = rem - r * 34;
      int wwg = mapidx(w0 + wi - 1, Ww, padmode);
      float v = ldany(xv, ((size_t)(ci0 + ci) * Hh + rows[r]) * Ww + wwg, isbf);
      if (ACTIN) { v += bias_in[ci0 + ci]; v = v > 0.f ? v : expm1f(v); }
      sx[ci][r][wi] = v;
    }
    __syncthreads();
#pragma unroll
    for (int ci = 0; ci < 8; ci++) {
      float wk[9];
      const float* wb = wp + (size_t)((ci0 + ci) * 9) * Cout + co;
#pragma unroll
      for (int k = 0; k < 9; k++) wk[k] = wb[(size_t)k * Cout];
#pragma unroll
      for (int r = 0; r < 3; r++) {
        float rv[PXT + 2];
        if constexpr (PXT == 8) {
          const float4* sv = (const float4*)&sx[ci][r][0];
          float4 a = sv[wl / 4], b = sv[wl / 4 + 1], c = sv[wl / 4 + 2];
          rv[0]=a.x; rv[1]=a.y; rv[2]=a.z; rv[3]=a.w;
          rv[4]=b.x; rv[5]=b.y; rv[6]=b.z; rv[7]=b.w;
          rv[8]=c.x; rv[9]=c.y;
        } else {
#pragma unroll
          for (int q = 0; q < PXT + 2; q++) rv[q] = sx[ci][r][wl + q];
        }
#pragma unroll
        for (int pxi = 0; pxi < PXT; pxi++)
          acc[pxi] = fmaf(wk[r * 3], rv[pxi],
                     fmaf(wk[r * 3 + 1], rv[pxi + 1],
                     fmaf(wk[r * 3 + 2], rv[pxi + 2], acc[pxi])));
      }
    }
  }
  if (ATOMIC) {
#pragma unroll
    for (int pxi = 0; pxi < PXT; pxi++) {
      size_t oi = ((size_t)co * Hh + h) * Ww + w0 + wl + pxi;
      atomicAdd(&((float*)out)[oi], acc[pxi]);
    }
  } else {
    float bv = bias[co];
    int obf = FINAL ? *flag : 0;
#pragma unroll
    for (int pxi = 0; pxi < PXT; pxi++) {
      float v = act_apply(acc[pxi] + bv, act);
      size_t oi = ((size_t)co * Hh + h) * Ww + w0 + wl + pxi;
      if (FINAL && obf) ((bf16*)out)[oi] = __float2bfloat16(v);
      else ((float*)out)[oi] = v;
    }
  }
}

// ---------------- head2 + per-gaussian prep ----------------
__global__ __launch_bounds__(128) void head2_prep_k(const float* __restrict__ h1,
    const float* __restrict__ smallf, const float* __restrict__ dispf,
    float* __restrict__ params, float* __restrict__ zbuf, int* __restrict__ rank) {
  const float* invK = smallf;
  const float* Km   = smallf + 16;
  const float* rw2  = smallf + 32;
  const float* rb2  = smallf + 320;
  const float* sw2  = smallf + 324;
  const float* sb2  = smallf + 486;
  const float* ow2  = smallf + 489;
  const float* ob2  = smallf + 507;
  int p = blockIdx.x * 128 + threadIdx.x;
  if (p >= NP) return;
  int hh = p / Ww, ww = p - hh * Ww;
  float racc[4], sacc[3], oacc;
#pragma unroll
  for (int i = 0; i < 4; i++) racc[i] = rb2[i];
#pragma unroll
  for (int i = 0; i < 3; i++) sacc[i] = sb2[i];
  oacc = ob2[0];
  for (int ci = 0; ci < 16; ci++) {
    float t9[9];
#pragma unroll
    for (int r = 0; r < 3; r++) {
      int rr = mapidx(hh + r - 1, Hh, 0);
#pragma unroll
      for (int s = 0; s < 3; s++) {
        int cc = mapidx(ww + s - 1, Ww, 0);
        t9[r * 3 + s] = h1[(size_t)ci * NP + rr * Ww + cc];
      }
    }
    if (ci < 8) {
      for (int co = 0; co < 4; co++)
#pragma unroll
        for (int k = 0; k < 9; k++)
          racc[co] = fmaf(t9[k], rw2[(co * 8 + ci) * 9 + k], racc[co]);
    } else if (ci < 14) {
      int c2 = ci - 8;
      for (int co = 0; co < 3; co++)
#pragma unroll
        for (int k = 0; k < 9; k++)
          sacc[co] = fmaf(t9[k], sw2[(co * 6 + c2) * 9 + k], sacc[co]);
    } else {
      int c2 = ci - 14;
#pragma unroll
      for (int k = 0; k < 9; k++)
        oacc = fmaf(t9[k], ow2[c2 * 9 + k], oacc);
    }
  }
  float nq = sqrtf(racc[0]*racc[0] + racc[1]*racc[1] + racc[2]*racc[2] + racc[3]*racc[3]);
  nq = fmaxf(nq, 1e-12f);
  float qw = racc[0] / nq, qx = racc[1] / nq, qy = racc[2] / nq, qz = racc[3] / nq;
  float s0 = fabsf(sacc[0]), s1 = fabsf(sacc[1]), s2 = fabsf(sacc[2]);
  float opa = 1.f / (1.f + __expf(-oacc));
  float d = dispf[p];
  float scaled = 0.01f + 9.99f * d;
  float depth = fminf(fmaxf(1.f / scaled, 0.1f), 100.f);
  float M00 = invK[0], M01 = invK[1], M02 = invK[2];
  float M10 = invK[4], M11 = invK[5], M12 = invK[6];
  float M20 = invK[8], M21 = invK[9], M22 = invK[10];
  float gxf = (float)ww, gyf = (float)hh;
  float X = (M00 * gxf + M01 * gyf + M02) * depth;
  float Y = (M10 * gxf + M11 * gyf + M12) * depth;
  float Z = (M20 * gxf + M21 * gyf + M22) * depth;
  float fxk = Km[0], fyk = Km[5];
  float cxk = Km[2], cyk = Km[6];
  float u = fxk * X / Z + cxk;
  float v = fyk * Y / Z + cyk;
  float R00 = 1.f - 2.f*(qy*qy + qz*qz), R01 = 2.f*(qx*qy - qw*qz), R02 = 2.f*(qx*qz + qw*qy);
  float R10 = 2.f*(qx*qy + qw*qz), R11 = 1.f - 2.f*(qx*qx + qz*qz), R12 = 2.f*(qy*qz - qw*qx);
  float R20 = 2.f*(qx*qz - qw*qy), R21 = 2.f*(qy*qz + qw*qx), R22 = 1.f - 2.f*(qx*qx + qy*qy);
  float M0a = R00*s0, M0b = R01*s1, M0c = R02*s2;
  float M1a = R10*s0, M1b = R11*s1, M1c = R12*s2;
  float M2a = R20*s0, M2b = R21*s1, M2c = R22*s2;
  float S00 = M0a*M0a + M0b*M0b + M0c*M0c;
  float S01 = M0a*M1a + M0b*M1b + M0c*M1c;
  float S02 = M0a*M2a + M0b*M2b + M0c*M2c;
  float S11 = M1a*M1a + M1b*M1b + M1c*M1c;
  float S12 = M1a*M2a + M1b*M2b + M1c*M2c;
  float S22 = M2a*M2a + M2b*M2b + M2c*M2c;
  float iz = 1.f / Z;
  float j00 = fxk * iz, j02 = -fxk * X * iz * iz;
  float j11 = fyk * iz, j12 = -fyk * Y * iz * iz;
  float c00 = j00*j00*S00 + 2.f*j00*j02*S02 + j02*j02*S22 + 0.3f;
  float c01 = j00*j11*S01 + j00*j12*S02 + j02*j11*S12 + j02*j12*S22;
  float c11 = j11*j11*S11 + 2.f*j11*j12*S12 + j12*j12*S22 + 0.3f;
  float det = c00 * c11 - c01 * c01;
  float idet = 1.f / det;
  float* pr = params + (size_t)p * 8;
  pr[0] = u; pr[1] = v; pr[2] = c11 * idet; pr[3] = -c01 * idet;
  pr[4] = c00 * idet; pr[5] = opa; pr[6] = Z; pr[7] = 0.f;
  zbuf[p] = Z;
  rank[p] = 0;
}

// ---------------- rank-by-count stable argsort (z ascending, idx tiebreak) ----------------
__global__ __launch_bounds__(256) void rank_count_k(const float* __restrict__ zbuf,
                                                    int* __restrict__ rank) {
  int i = blockIdx.x * 256 + threadIdx.x;
  int sid = blockIdx.y;
  float zi = zbuf[i];
  const float4* zv = (const float4*)(zbuf + sid * 960);
  int cnt = 0;
  for (int t = 0; t < 240; t++) {
    float4 z4 = zv[t];
    int jb = sid * 960 + t * 4;
    cnt += (z4.x < zi || (z4.x == zi && jb + 0 < i)) ? 1 : 0;
    cnt += (z4.y < zi || (z4.y == zi && jb + 1 < i)) ? 1 : 0;
    cnt += (z4.z < zi || (z4.z == zi && jb + 2 < i)) ? 1 : 0;
    cnt += (z4.w < zi || (z4.w == zi && jb + 3 < i)) ? 1 : 0;
  }
  atomicAdd(&rank[i], cnt);
}

__global__ __launch_bounds__(256) void scatter_k(const int* __restrict__ rank,
                                                 int* __restrict__ ord) {
  int i = blockIdx.x * 256 + threadIdx.x;
  ord[rank[i]] = i;
}

// ---------------- gather into sorted order (+ elu(t2+b2), + zero lev) ----------------
__global__ __launch_bounds__(256) void gather_k(const int* __restrict__ ord,
    const float* __restrict__ params, const float* __restrict__ t2r,
    const float* __restrict__ fb2, float* __restrict__ params_s,
    float* __restrict__ feat_s, float* __restrict__ lev) {
  int gid = blockIdx.x * 256 + threadIdx.x;   // NP*64
  int n = gid >> 6, c = gid & 63;
  int orig = ord[n];
  float v = t2r[(size_t)c * NP + orig] + fb2[c];
  feat_s[gid] = v > 0.f ? v : expm1f(v);
  lev[gid] = 0.f;
  if (c < 8) params_s[(n << 3) + c] = params[((size_t)orig << 3) + c];
}

// ---------------- pass A: per-chunk transmittance ----------------
__global__ __launch_bounds__(256) void alpha_k(const float* __restrict__ params_s,
    float* __restrict__ tch) {
  const int p = blockIdx.x * 256 + threadIdx.x;
  const int ch = blockIdx.y;
  const float px = (float)(p % Ww), py = (float)(p / Ww);
  float T = 1.f;
  const float4* pv = (const float4*)params_s + (size_t)ch * CHSZ * 2;
  for (int n0 = 0; n0 < CHSZ; n0 += 4) {
    float4 pa[4], pb[4];
#pragma unroll
    for (int u = 0; u < 4; u++) { pa[u] = pv[(n0 + u) * 2]; pb[u] = pv[(n0 + u) * 2 + 1]; }
#pragma unroll
    for (int u = 0; u < 4; u++) {
      float dx = px - pa[u].x, dy = py - pa[u].y;
      float power = -0.5f * (pa[u].z * dx * dx + pb[u].x * dy * dy) - pa[u].w * dx * dy;
      if (__any(power > -18.f)) {   // alpha<1.6e-8: T*(1-a) rounds to T in fp32
        float al = fminf(pb[u].y * __expf(power), 0.99f);
        T *= 1.f - al;
      }
    }
  }
  tch[(size_t)ch * NP + p] = T;
}

// ---------------- pass B: features, seeded by prefix transmittance ----------------
__global__ __launch_bounds__(128) void raster_k(const float* __restrict__ params_s,
    const float* __restrict__ feat_s, const float* __restrict__ tch,
    float* __restrict__ lev) {
  const int p = blockIdx.x * 128 + threadIdx.x;
  const int ch = blockIdx.y;
  float Ts = 1.f;
  for (int c = 0; c < ch; c++) Ts *= tch[(size_t)c * NP + p];
  const float px = (float)(p % Ww), py = (float)(p / Ww);
  float4 acc[16];
#pragma unroll
  for (int q = 0; q < 16; q++) acc[q] = make_float4(0.f, 0.f, 0.f, 0.f);
  float T = 1.f;
  const int g0 = ch * CHSZ;
  const float4* pv = (const float4*)params_s + (size_t)g0 * 2;
  for (int n0 = 0; n0 < CHSZ; n0 += 4) {
    float4 pa[4], pb[4];
#pragma unroll
    for (int u = 0; u < 4; u++) { pa[u] = pv[(n0 + u) * 2]; pb[u] = pv[(n0 + u) * 2 + 1]; }
#pragma unroll
    for (int u = 0; u < 4; u++) {
      float dx = px - pa[u].x, dy = py - pa[u].y;
      float power = -0.5f * (pa[u].z * dx * dx + pb[u].x * dy * dy) - pa[u].w * dx * dy;
      if (__any(power > -18.f)) {
        float al = fminf(pb[u].y * __expf(power), 0.99f);
        float wgt = al * T;
        T *= 1.f - al;
        if (__any(wgt > 0.f)) {
          const float4* fr = (const float4*)(feat_s + (((size_t)(g0 + n0 + u)) << 6));
#pragma unroll
          for (int q = 0; q < 16; q++) {
            float4 f = fr[q];
            acc[q].x = fmaf(wgt, f.x, acc[q].x);
            acc[q].y = fmaf(wgt, f.y, acc[q].y);
            acc[q].z = fmaf(wgt, f.z, acc[q].z);
            acc[q].w = fmaf(wgt, f.w, acc[q].w);
          }
        }
      }
    }
  }
#pragma unroll
  for (int q = 0; q < 16; q++) {
    atomicAdd(&lev[(size_t)(q * 4 + 0) * NP + p], Ts * acc[q].x);
    atomicAdd(&lev[(size_t)(q * 4 + 1) * NP + p], Ts * acc[q].y);
    atomicAdd(&lev[(size_t)(q * 4 + 2) * NP + p], Ts * acc[q].z);
    atomicAdd(&lev[(size_t)(q * 4 + 3) * NP + p], Ts * acc[q].w);
  }
}

extern "C" void kernel_launch(void* const* d_in, const int* in_sizes, int n_in,
                              void* d_out, int out_size, void* d_ws, size_t ws_size,
                              hipStream_t stream) {
  (void)in_sizes; (void)n_in; (void)out_size; (void)ws_size;
  const void* init_feature = d_in[0];
  const void* disp   = d_in[1];
  const void* invK   = d_in[2];
  const void* Km     = d_in[3];
  const void* rot_w1 = d_in[4];
  const void* rot_b1 = d_in[5];
  const void* rot_w2 = d_in[6];
  const void* rot_b2 = d_in[7];
  const void* scl_w1 = d_in[8];
  const void* scl_b1 = d_in[9];
  const void* scl_w2 = d_in[10];
  const void* scl_b2 = d_in[11];
  const void* opa_w1 = d_in[12];
  const void* opa_b1 = d_in[13];
  const void* opa_w2 = d_in[14];
  const void* opa_b2 = d_in[15];
  const void* fl_w1  = d_in[16];
  const void* fl_b1  = d_in[17];
  const void* fl_w2  = d_in[18];
  const void* fl_b2  = d_in[19];
  const void* fr_w   = d_in[20];
  const void* fr_b   = d_in[21];

  float* wsf = (float*)d_ws;
  // layout (floats); total 3,294,224 f = 13.18 MB (< 16.6 MB proven in R1)
  int*   flag    = (int*)wsf;                   // @0        16
  float* smallf  = wsf + 16;                    // 512
  float* dispf   = wsf + 528;                   // 7680
  float* biasf   = wsf + 8208;                  // 512
  float* wp_h1   = wsf + 8720;                  // 18432
  float* wp_fl1  = wsf + 27152;                 // 147456
  float* wp_fl2  = wsf + 174608;                // 73728
  float* wp_fr   = wsf + 248336;                // 73728
  float* params_s= wsf + 322064;                // 61440
  float* feat_s  = wsf + 383504;                // 491520
  float* tch     = wsf + 875024;                // 32*7680 = 245760
  float* lev     = wsf + 1120784;               // 491520
  float* t1r     = wsf + 1612304;               // 983040 (raw conv1, pre-bias/act)
  float* h1      = wsf + 2595344;               // 122880
  float* t2r     = wsf + 2718224;               // 491520 (raw conv2, pre-bias/act)
  float* params  = wsf + 3209744;               // 61440
  float* zbuf    = wsf + 3271184;               // 7680
  int*   rank    = (int*)(wsf + 3278864);       // 7680
  int*   ord     = (int*)(wsf + 3286544);       // 7680

  // dtype sniff, then one merged prep launch (converts + repacks + zero t1r/t2r)
  sniff_k<<<1, 256, 0, stream>>>((const unsigned short*)fl_w1, flag);
  prep_k<<<7018, 256, 0, stream>>>(flag,
      disp, invK, Km, rot_w2, rot_b2, scl_w2, scl_b2, opa_w2, opa_b2,
      rot_b1, scl_b1, opa_b1, fl_b1, fl_b2, fr_b,
      fl_w1, fl_w2, fr_w, rot_w1, scl_w1, opa_w1,
      dispf, smallf, biasf, wp_fl1, wp_fl2, wp_fr, wp_h1, t1r, t2r);

  // heads first conv (16 ch, edge, gelu): COB=16 PXT=2, direct epilogue
  conv_tiled_k<true, false, 16, 2, false, false><<<dim3(5, 48, 1), 256, 0, stream>>>(
      init_feature, wp_h1, biasf, nullptr, h1, flag, 16, 0, 2, 1, 128);
  // fl1 (128->128, reflect): 2 co-blocks x 4 ci-quarters, atomic raw sums into t1r
  conv_tiled_k<true, false, 64, 8, false, true><<<dim3(5, 48, 8), 256, 0, stream>>>(
      init_feature, wp_fl1, nullptr, nullptr, t1r, flag, 128, 1, 0, 2, 32);
  // fl2 (128->64, reflect): staging applies elu(t1r+fl_b1); 4 ci-quarters, atomic into t2r
  conv_tiled_k<false, false, 64, 8, true, true><<<dim3(5, 48, 4), 256, 0, stream>>>(
      t1r, wp_fl2, nullptr, biasf + 16, t2r, flag, 64, 1, 0, 1, 32);
  // heads second conv + gaussian prep (+ zbuf, rank=0)
  head2_prep_k<<<60, 128, 0, stream>>>(h1, smallf, dispf, params, zbuf, rank);
  // stable argsort by z via rank-count, then scatter + gather (elu(t2r+b2), zero lev)
  rank_count_k<<<dim3(30, 8), 256, 0, stream>>>(zbuf, rank);
  scatter_k<<<30, 256, 0, stream>>>(rank, ord);
  gather_k<<<(NP * 64) / 256, 256, 0, stream>>>(ord, params, t2r, biasf + 144,
                                                params_s, feat_s, lev);
  // two-pass raster: chunk transmittances, then features + atomic combine
  alpha_k<<<dim3(NP / 256, NCHUNK), 256, 0, stream>>>(params_s, tch);
  raster_k<<<dim3(NP / 128, NCHUNK), 128, 0, stream>>>(params_s, feat_s, tch, lev);
  // final conv (64->128, reflect, elu): 4 co-blocks of 32, direct epilogue, dtype per flag
  conv_tiled_k<false, true, 32, 4, false, false><<<dim3(5, 48, 4), 256, 0, stream>>>(
      lev, wp_fr, biasf + 208, nullptr, d_out, flag, 128, 1, 1, 4, 64);
}

// Round 10
// 593.605 us; speedup vs baseline: 2.0127x; 1.3842x over previous
//
#include <hip/hip_runtime.h>
#include <hip/hip_bf16.h>
#include <math.h>

#define Hh 48
#define Ww 160
#define NP 7680      // H*W
#define NCHUNK 32
#define CHSZ (NP / NCHUNK) // 240

using bf16 = __hip_bfloat16;
typedef __attribute__((ext_vector_type(8))) short v8s;
typedef __attribute__((ext_vector_type(4))) float v4f;

__device__ __forceinline__ float bfdec(unsigned short u) {
  return __uint_as_float(((unsigned)u) << 16);
}
__device__ __forceinline__ unsigned short bfenc(float x) {
  bf16 b = __float2bfloat16(x);
  return *(unsigned short*)&b;
}
__device__ __forceinline__ float ldany(const void* p, size_t i, int isbf) {
  return isbf ? bfdec(((const unsigned short*)p)[i]) : ((const float*)p)[i];
}

__device__ __forceinline__ int mapidx(int i, int n, int mode) {
  if (mode == 0) return i < 0 ? 0 : (i >= n ? n - 1 : i);       // edge
  return i < 0 ? -i : (i >= n ? 2 * n - 2 - i : i);             // reflect
}

__device__ __forceinline__ float eluf(float v) { return v > 0.f ? v : expm1f(v); }
__device__ __forceinline__ float geluf(float v) {
  float c = v + 0.044715f * v * v * v;
  return 0.5f * v * (1.f + tanhf(0.7978845608028654f * c));
}

// ---------------- dtype sniffer (R2-proven) ----------------
__global__ __launch_bounds__(256) void sniff_k(const unsigned short* __restrict__ w,
                                               int* __restrict__ flag) {
  __shared__ int cnt[256];
  int c = 0;
  for (int i = threadIdx.x; i < 2048; i += 256) {
    float a = fabsf(bfdec(w[i]));
    if (a > 1e-3f && a < 0.5f) c++;
  }
  cnt[threadIdx.x] = c;
  __syncthreads();
  for (int s = 128; s > 0; s >>= 1) {
    if (threadIdx.x < s) cnt[threadIdx.x] += cnt[threadIdx.x + s];
    __syncthreads();
  }
  if (threadIdx.x == 0) flag[0] = (cnt[0] > 1536) ? 1 : 0;
}

// ---------------- merged prep: cvt + bf16 operand builds, one launch ----------------
// segments: disp 7680 | small 508 | bias 336 | rot1 9216 | scl1 6912 | opa1 2304
//           | a_fl1 147456 | a_fl2 73728 | a_fr 73728 | xb 983040
__global__ __launch_bounds__(256) void prep_k(const int* __restrict__ flag,
    const void* disp, const void* invK, const void* K, const void* rw2,
    const void* rb2, const void* sw2, const void* sb2, const void* ow2, const void* ob2,
    const void* rb1, const void* sb1, const void* ob1, const void* fb1, const void* fb2,
    const void* frb, const void* rot_w1, const void* scl_w1, const void* opa_w1,
    const void* fl_w1, const void* fl_w2, const void* fr_w, const void* xsrc,
    float* __restrict__ dispf, float* __restrict__ smallf, float* __restrict__ biasf,
    float* __restrict__ wp_h1, unsigned short* __restrict__ a_fl1,
    unsigned short* __restrict__ a_fl2, unsigned short* __restrict__ a_fr,
    unsigned short* __restrict__ xb) {
  int i = blockIdx.x * 256 + threadIdx.x;
  int f = *flag;
  if (i < 7680) { dispf[i] = ldany(disp, i, f); return; }
  i -= 7680;
  if (i < 508) {
    // invK@0(16) K@16(16) rw2@32(288) rb2@320(4) sw2@324(162) sb2@486(3) ow2@489(18) ob2@507(1)
    const void* src; int off;
    if (i < 16)       { src = invK; off = i; }
    else if (i < 32)  { src = K;    off = i - 16; }
    else if (i < 320) { src = rw2;  off = i - 32; }
    else if (i < 324) { src = rb2;  off = i - 320; }
    else if (i < 486) { src = sw2;  off = i - 324; }
    else if (i < 489) { src = sb2;  off = i - 486; }
    else if (i < 507) { src = ow2;  off = i - 489; }
    else              { src = ob2;  off = i - 507; }
    smallf[i] = ldany(src, off, f); return;
  }
  i -= 508;
  if (i < 336) {
    // [0,16) head1 (rot8,scl6,opa2); [16,144) fl_b1; [144,208) fl_b2; [208,336) fr_b
    if (i < 8) biasf[i] = ldany(rb1, i, f);
    else if (i < 14) biasf[i] = ldany(sb1, i - 8, f);
    else if (i < 16) biasf[i] = ldany(ob1, i - 14, f);
    else if (i < 144) biasf[i] = ldany(fb1, i - 16, f);
    else if (i < 208) biasf[i] = ldany(fb2, i - 144, f);
    else biasf[i] = ldany(frb, i - 208, f);
    return;
  }
  i -= 336;
  if (i < 9216) { int co = i / 1152, rem = i - co * 1152;
    wp_h1[(size_t)rem * 16 + co] = ldany(rot_w1, i, f); return; }
  i -= 9216;
  if (i < 6912) { int co = i / 1152, rem = i - co * 1152;
    wp_h1[(size_t)rem * 16 + 8 + co] = ldany(scl_w1, i, f); return; }
  i -= 6912;
  if (i < 2304) { int co = i / 1152, rem = i - co * 1152;
    wp_h1[(size_t)rem * 16 + 14 + co] = ldany(opa_w1, i, f); return; }
  i -= 2304;
  if (i < 147456) { a_fl1[i] = bfenc(ldany(fl_w1, i, f)); return; }
  i -= 147456;
  if (i < 73728) { a_fl2[i] = bfenc(ldany(fl_w2, i, f)); return; }
  i -= 73728;
  if (i < 73728) { a_fr[i] = bfenc(ldany(fr_w, i, f)); return; }
  i -= 73728;
  if (i < 983040) { xb[i] = bfenc(ldany(xsrc, i, f)); return; }
}

// ---------------- head first conv (128->16, edge, gelu) — VALU, flag-driven ----------------
__global__ __launch_bounds__(256) void head_conv_k(const void* __restrict__ xv,
    const float* __restrict__ wp, const float* __restrict__ bias,
    const int* __restrict__ flag, float* __restrict__ out) {
  __shared__ float sx[8][3][36];
  const int h = blockIdx.y;
  const int w0 = blockIdx.x * 32;
  const int coL = threadIdx.x & 15;
  const int wg = threadIdx.x >> 4;
  const int wl = wg * 2;
  const int isbf = *flag;
  float acc[2] = {0.f, 0.f};
  int rows[3];
#pragma unroll
  for (int r = 0; r < 3; r++) rows[r] = mapidx(h + r - 1, Hh, 0);
  for (int ci0 = 0; ci0 < 128; ci0 += 8) {
    __syncthreads();
    for (int idx = threadIdx.x; idx < 816; idx += 256) {
      int ci = idx / 102; int rem = idx - ci * 102;
      int r = rem / 34;   int wi = rem - r * 34;
      int wwg = mapidx(w0 + wi - 1, Ww, 0);
      sx[ci][r][wi] = ldany(xv, ((size_t)(ci0 + ci) * Hh + rows[r]) * Ww + wwg, isbf);
    }
    __syncthreads();
#pragma unroll
    for (int ci = 0; ci < 8; ci++) {
      float wk[9];
      const float* wb = wp + (size_t)((ci0 + ci) * 9) * 16 + coL;
#pragma unroll
      for (int k = 0; k < 9; k++) wk[k] = wb[(size_t)k * 16];
#pragma unroll
      for (int r = 0; r < 3; r++) {
        float rv[4];
#pragma unroll
        for (int q = 0; q < 4; q++) rv[q] = sx[ci][r][wl + q];
#pragma unroll
        for (int pxi = 0; pxi < 2; pxi++)
          acc[pxi] = fmaf(wk[r * 3], rv[pxi],
                     fmaf(wk[r * 3 + 1], rv[pxi + 1],
                     fmaf(wk[r * 3 + 2], rv[pxi + 2], acc[pxi])));
      }
    }
  }
  float bv = bias[coL];
#pragma unroll
  for (int pxi = 0; pxi < 2; pxi++)
    out[((size_t)coL * Hh + h) * Ww + w0 + wl + pxi] = geluf(acc[pxi] + bv);
}

// ---------------- MFMA implicit-GEMM 3x3 reflect conv ----------------
// C[co][px] = elu( sum_k A[co][k]*B[px][k] + bias[co] ), k = ci*9+tap.
// A = bf16 weights [Cout][K]; X = bf16 image [Cin][H*W]. OM: 0=f32 out, 1=bf16 out,
// 2=flag-driven (d_out). Block 4 waves; tile 64co x 128px; BK=32. grid (60, Cout/64).
template<int OM>
__global__ __launch_bounds__(256) void gemm_conv_k(const unsigned short* __restrict__ A,
    const unsigned short* __restrict__ X, const float* __restrict__ bias,
    void* __restrict__ out, const int* __restrict__ flag, int K) {
  __shared__ v8s As4[64][5];     // [co][kgroup], [4]=pad (80 B row stride)
  __shared__ v8s Bs4[128][5];
  __shared__ int off9s[128][9];
  const int tid = threadIdx.x;
  const int pxB = blockIdx.x * 128;
  const int coB = blockIdx.y * 64;
  if (tid < 128) {
    int p = pxB + tid;
    int h = p / Ww, w = p - h * Ww;
#pragma unroll
    for (int r = 0; r < 3; r++) {
      int hh = mapidx(h + r - 1, Hh, 1);
#pragma unroll
      for (int s = 0; s < 3; s++)
        off9s[tid][r * 3 + s] = hh * Ww + mapidx(w + s - 1, Ww, 1);
    }
  }
  const int lane = tid & 63, wv = tid >> 6;
  const int wy = wv >> 1, wx = wv & 1;
  const int m16 = lane & 15, quad = lane >> 4;
  const int aco = tid >> 2, ag = tid & 3;
  const int pxl = tid & 127, bg0 = (tid >> 7) * 2;
  v4f acc[2][4];
#pragma unroll
  for (int a = 0; a < 2; a++)
#pragma unroll
    for (int b = 0; b < 4; b++) acc[a][b] = (v4f){0.f, 0.f, 0.f, 0.f};
  __syncthreads();
  const int nIter = K >> 5;
  for (int it = 0; it < nIter; it++) {
    const int k0 = it << 5;
    {
      const unsigned short* ap = &A[(size_t)(coB + aco) * K + k0 + ag * 8];
      v8s av;
#pragma unroll
      for (int j = 0; j < 8; j++) av[j] = (short)ap[j];
      As4[aco][ag] = av;
    }
#pragma unroll
    for (int gi = 0; gi < 2; gi++) {
      int g = bg0 + gi;
      v8s bv;
#pragma unroll
      for (int j = 0; j < 8; j++) {
        int k = k0 + g * 8 + j;
        int ci = k / 9;
        int t = k - ci * 9;
        bv[j] = (short)X[(size_t)ci * NP + off9s[pxl][t]];
      }
      Bs4[pxl][g] = bv;
    }
    __syncthreads();
    v8s af[2], bfr[4];
#pragma unroll
    for (int a = 0; a < 2; a++) af[a] = As4[wy * 32 + a * 16 + m16][quad];
#pragma unroll
    for (int b = 0; b < 4; b++) bfr[b] = Bs4[wx * 64 + b * 16 + m16][quad];
#pragma unroll
    for (int a = 0; a < 2; a++)
#pragma unroll
      for (int b = 0; b < 4; b++)
        acc[a][b] = __builtin_amdgcn_mfma_f32_16x16x32_bf16(af[a], bfr[b], acc[a][b], 0, 0, 0);
    __syncthreads();
  }
  const int obf = (OM == 2) ? *flag : (OM == 1);
  // D[m=co][n=px]: row(M)=quad*4+r, col(N)=lane&15
#pragma unroll
  for (int a = 0; a < 2; a++) {
#pragma unroll
    for (int b = 0; b < 4; b++) {
#pragma unroll
      for (int r = 0; r < 4; r++) {
        int co = coB + wy * 32 + a * 16 + quad * 4 + r;
        int px = pxB + wx * 64 + b * 16 + m16;
        float v = eluf(acc[a][b][r] + bias[co]);
        size_t oi = (size_t)co * NP + px;
        if (obf) ((unsigned short*)out)[oi] = bfenc(v);
        else ((float*)out)[oi] = v;
      }
    }
  }
}

// ---------------- head2 + per-gaussian prep ----------------
__global__ __launch_bounds__(128) void head2_prep_k(const float* __restrict__ h1,
    const float* __restrict__ smallf, const float* __restrict__ dispf,
    float* __restrict__ params, float* __restrict__ zbuf, int* __restrict__ rank) {
  const float* invK = smallf;
  const float* Km   = smallf + 16;
  const float* rw2  = smallf + 32;
  const float* rb2  = smallf + 320;
  const float* sw2  = smallf + 324;
  const float* sb2  = smallf + 486;
  const float* ow2  = smallf + 489;
  const float* ob2  = smallf + 507;
  int p = blockIdx.x * 128 + threadIdx.x;
  if (p >= NP) return;
  int hh = p / Ww, ww = p - hh * Ww;
  float racc[4], sacc[3], oacc;
#pragma unroll
  for (int i = 0; i < 4; i++) racc[i] = rb2[i];
#pragma unroll
  for (int i = 0; i < 3; i++) sacc[i] = sb2[i];
  oacc = ob2[0];
  for (int ci = 0; ci < 16; ci++) {
    float t9[9];
#pragma unroll
    for (int r = 0; r < 3; r++) {
      int rr = mapidx(hh + r - 1, Hh, 0);
#pragma unroll
      for (int s = 0; s < 3; s++) {
        int cc = mapidx(ww + s - 1, Ww, 0);
        t9[r * 3 + s] = h1[(size_t)ci * NP + rr * Ww + cc];
      }
    }
    if (ci < 8) {
      for (int co = 0; co < 4; co++)
#pragma unroll
        for (int k = 0; k < 9; k++)
          racc[co] = fmaf(t9[k], rw2[(co * 8 + ci) * 9 + k], racc[co]);
    } else if (ci < 14) {
      int c2 = ci - 8;
      for (int co = 0; co < 3; co++)
#pragma unroll
        for (int k = 0; k < 9; k++)
          sacc[co] = fmaf(t9[k], sw2[(co * 6 + c2) * 9 + k], sacc[co]);
    } else {
      int c2 = ci - 14;
#pragma unroll
      for (int k = 0; k < 9; k++)
        oacc = fmaf(t9[k], ow2[c2 * 9 + k], oacc);
    }
  }
  float nq = sqrtf(racc[0]*racc[0] + racc[1]*racc[1] + racc[2]*racc[2] + racc[3]*racc[3]);
  nq = fmaxf(nq, 1e-12f);
  float qw = racc[0] / nq, qx = racc[1] / nq, qy = racc[2] / nq, qz = racc[3] / nq;
  float s0 = fabsf(sacc[0]), s1 = fabsf(sacc[1]), s2 = fabsf(sacc[2]);
  float opa = 1.f / (1.f + __expf(-oacc));
  float d = dispf[p];
  float scaled = 0.01f + 9.99f * d;
  float depth = fminf(fmaxf(1.f / scaled, 0.1f), 100.f);
  float M00 = invK[0], M01 = invK[1], M02 = invK[2];
  float M10 = invK[4], M11 = invK[5], M12 = invK[6];
  float M20 = invK[8], M21 = invK[9], M22 = invK[10];
  float gxf = (float)ww, gyf = (float)hh;
  float X = (M00 * gxf + M01 * gyf + M02) * depth;
  float Y = (M10 * gxf + M11 * gyf + M12) * depth;
  float Z = (M20 * gxf + M21 * gyf + M22) * depth;
  float fxk = Km[0], fyk = Km[5];
  float cxk = Km[2], cyk = Km[6];
  float u = fxk * X / Z + cxk;
  float v = fyk * Y / Z + cyk;
  float R00 = 1.f - 2.f*(qy*qy + qz*qz), R01 = 2.f*(qx*qy - qw*qz), R02 = 2.f*(qx*qz + qw*qy);
  float R10 = 2.f*(qx*qy + qw*qz), R11 = 1.f - 2.f*(qx*qx + qz*qz), R12 = 2.f*(qy*qz - qw*qx);
  float R20 = 2.f*(qx*qz - qw*qy), R21 = 2.f*(qy*qz + qw*qx), R22 = 1.f - 2.f*(qx*qx + qy*qy);
  float M0a = R00*s0, M0b = R01*s1, M0c = R02*s2;
  float M1a = R10*s0, M1b = R11*s1, M1c = R12*s2;
  float M2a = R20*s0, M2b = R21*s1, M2c = R22*s2;
  float S00 = M0a*M0a + M0b*M0b + M0c*M0c;
  float S01 = M0a*M1a + M0b*M1b + M0c*M1c;
  float S02 = M0a*M2a + M0b*M2b + M0c*M2c;
  float S11 = M1a*M1a + M1b*M1b + M1c*M1c;
  float S12 = M1a*M2a + M1b*M2b + M1c*M2c;
  float S22 = M2a*M2a + M2b*M2b + M2c*M2c;
  float iz = 1.f / Z;
  float j00 = fxk * iz, j02 = -fxk * X * iz * iz;
  float j11 = fyk * iz, j12 = -fyk * Y * iz * iz;
  float c00 = j00*j00*S00 + 2.f*j00*j02*S02 + j02*j02*S22 + 0.3f;
  float c01 = j00*j11*S01 + j00*j12*S02 + j02*j11*S12 + j02*j12*S22;
  float c11 = j11*j11*S11 + 2.f*j11*j12*S12 + j12*j12*S22 + 0.3f;
  float det = c00 * c11 - c01 * c01;
  float idet = 1.f / det;
  float* pr = params + (size_t)p * 8;
  pr[0] = u; pr[1] = v; pr[2] = c11 * idet; pr[3] = -c01 * idet;
  pr[4] = c00 * idet; pr[5] = opa; pr[6] = Z; pr[7] = 0.f;
  zbuf[p] = Z;
  rank[p] = 0;
}

// ---------------- rank-by-count stable argsort ----------------
__global__ __launch_bounds__(256) void rank_count_k(const float* __restrict__ zbuf,
                                                    int* __restrict__ rank) {
  int i = blockIdx.x * 256 + threadIdx.x;
  int sid = blockIdx.y;
  float zi = zbuf[i];
  const float4* zv = (const float4*)(zbuf + sid * 960);
  int cnt = 0;
  for (int t = 0; t < 240; t++) {
    float4 z4 = zv[t];
    int jb = sid * 960 + t * 4;
    cnt += (z4.x < zi || (z4.x == zi && jb + 0 < i)) ? 1 : 0;
    cnt += (z4.y < zi || (z4.y == zi && jb + 1 < i)) ? 1 : 0;
    cnt += (z4.z < zi || (z4.z == zi && jb + 2 < i)) ? 1 : 0;
    cnt += (z4.w < zi || (z4.w == zi && jb + 3 < i)) ? 1 : 0;
  }
  atomicAdd(&rank[i], cnt);
}

__global__ __launch_bounds__(256) void scatter_k(const int* __restrict__ rank,
                                                 int* __restrict__ ord) {
  int i = blockIdx.x * 256 + threadIdx.x;
  ord[rank[i]] = i;
}

// ---------------- gather into sorted order + zero lev ----------------
__global__ __launch_bounds__(256) void gather_k(const int* __restrict__ ord,
    const float* __restrict__ params, const float* __restrict__ t2e,
    float* __restrict__ params_s, float* __restrict__ feat_s, float* __restrict__ lev) {
  int gid = blockIdx.x * 256 + threadIdx.x;   // NP*64
  int n = gid >> 6, c = gid & 63;
  int orig = ord[n];
  feat_s[gid] = t2e[(size_t)c * NP + orig];
  lev[gid] = 0.f;
  if (c < 8) params_s[(n << 3) + c] = params[((size_t)orig << 3) + c];
}

// ---------------- pass A: per-chunk transmittance ----------------
__global__ __launch_bounds__(256) void alpha_k(const float* __restrict__ params_s,
    float* __restrict__ tch) {
  const int p = blockIdx.x * 256 + threadIdx.x;
  const int ch = blockIdx.y;
  const float px = (float)(p % Ww), py = (float)(p / Ww);
  float T = 1.f;
  const float4* pv = (const float4*)params_s + (size_t)ch * CHSZ * 2;
  for (int n0 = 0; n0 < CHSZ; n0 += 4) {
    float4 pa[4], pb[4];
#pragma unroll
    for (int u = 0; u < 4; u++) { pa[u] = pv[(n0 + u) * 2]; pb[u] = pv[(n0 + u) * 2 + 1]; }
#pragma unroll
    for (int u = 0; u < 4; u++) {
      float dx = px - pa[u].x, dy = py - pa[u].y;
      float power = -0.5f * (pa[u].z * dx * dx + pb[u].x * dy * dy) - pa[u].w * dx * dy;
      if (__any(power > -18.f)) {   // alpha<1.6e-8: T*(1-a) rounds to T in fp32
        float al = fminf(pb[u].y * __expf(power), 0.99f);
        T *= 1.f - al;
      }
    }
  }
  tch[(size_t)ch * NP + p] = T;
}

// ---------------- pass B: features, seeded by prefix transmittance ----------------
__global__ __launch_bounds__(128) void raster_k(const float* __restrict__ params_s,
    const float* __restrict__ feat_s, const float* __restrict__ tch,
    float* __restrict__ lev) {
  const int p = blockIdx.x * 128 + threadIdx.x;
  const int ch = blockIdx.y;
  float Ts = 1.f;
  for (int c = 0; c < ch; c++) Ts *= tch[(size_t)c * NP + p];
  const float px = (float)(p % Ww), py = (float)(p / Ww);
  float4 acc[16];
#pragma unroll
  for (int q = 0; q < 16; q++) acc[q] = make_float4(0.f, 0.f, 0.f, 0.f);
  float T = 1.f;
  const int g0 = ch * CHSZ;
  const float4* pv = (const float4*)params_s + (size_t)g0 * 2;
  for (int n0 = 0; n0 < CHSZ; n0 += 4) {
    float4 pa[4], pb[4];
#pragma unroll
    for (int u = 0; u < 4; u++) { pa[u] = pv[(n0 + u) * 2]; pb[u] = pv[(n0 + u) * 2 + 1]; }
#pragma unroll
    for (int u = 0; u < 4; u++) {
      float dx = px - pa[u].x, dy = py - pa[u].y;
      float power = -0.5f * (pa[u].z * dx * dx + pb[u].x * dy * dy) - pa[u].w * dx * dy;
      if (__any(power > -18.f)) {
        float al = fminf(pb[u].y * __expf(power), 0.99f);
        float wgt = al * T;
        T *= 1.f - al;
        if (__any(wgt > 0.f)) {
          const float4* fr = (const float4*)(feat_s + (((size_t)(g0 + n0 + u)) << 6));
#pragma unroll
          for (int q = 0; q < 16; q++) {
            float4 f = fr[q];
            acc[q].x = fmaf(wgt, f.x, acc[q].x);
            acc[q].y = fmaf(wgt, f.y, acc[q].y);
            acc[q].z = fmaf(wgt, f.z, acc[q].z);
            acc[q].w = fmaf(wgt, f.w, acc[q].w);
          }
        }
      }
    }
  }
#pragma unroll
  for (int q = 0; q < 16; q++) {
    atomicAdd(&lev[(size_t)(q * 4 + 0) * NP + p], Ts * acc[q].x);
    atomicAdd(&lev[(size_t)(q * 4 + 1) * NP + p], Ts * acc[q].y);
    atomicAdd(&lev[(size_t)(q * 4 + 2) * NP + p], Ts * acc[q].z);
    atomicAdd(&lev[(size_t)(q * 4 + 3) * NP + p], Ts * acc[q].w);
  }
}

// ---------------- lev fp32 -> bf16 ----------------
__global__ __launch_bounds__(256) void cvt_lev_k(const float* __restrict__ lev,
                                                 unsigned short* __restrict__ levb) {
  int i = blockIdx.x * 256 + threadIdx.x;
  levb[i] = bfenc(lev[i]);
}

extern "C" void kernel_launch(void* const* d_in, const int* in_sizes, int n_in,
                              void* d_out, int out_size, void* d_ws, size_t ws_size,
                              hipStream_t stream) {
  (void)in_sizes; (void)n_in; (void)out_size; (void)ws_size;
  const void* init_feature = d_in[0];
  const void* disp   = d_in[1];
  const void* invK   = d_in[2];
  const void* Km     = d_in[3];
  const void* rot_w1 = d_in[4];
  const void* rot_b1 = d_in[5];
  const void* rot_w2 = d_in[6];
  const void* rot_b2 = d_in[7];
  const void* scl_w1 = d_in[8];
  const void* scl_b1 = d_in[9];
  const void* scl_w2 = d_in[10];
  const void* scl_b2 = d_in[11];
  const void* opa_w1 = d_in[12];
  const void* opa_b1 = d_in[13];
  const void* opa_w2 = d_in[14];
  const void* opa_b2 = d_in[15];
  const void* fl_w1  = d_in[16];
  const void* fl_b1  = d_in[17];
  const void* fl_w2  = d_in[18];
  const void* fl_b2  = d_in[19];
  const void* fr_w   = d_in[20];
  const void* fr_b   = d_in[21];

  float* wsf = (float*)d_ws;
  // layout (floats); total 2,778,128 f = 11.1 MB (< 16.6 MB proven in R2)
  int*   flag    = (int*)wsf;                   // @0        16
  float* smallf  = wsf + 16;                    // 512
  float* dispf   = wsf + 528;                   // 7680
  float* biasf   = wsf + 8208;                  // 512
  float* wp_h1   = wsf + 8720;                  // 18432
  unsigned short* a_fl1 = (unsigned short*)(wsf + 27152);   // 147456 us = 73728 f
  unsigned short* a_fl2 = (unsigned short*)(wsf + 100880);  // 73728 us = 36864 f
  unsigned short* a_fr  = (unsigned short*)(wsf + 137744);  // 73728 us = 36864 f
  unsigned short* xb    = (unsigned short*)(wsf + 174608);  // 983040 us = 491520 f... (245760 f? no: 983040/2=491520 f)
  unsigned short* t1b   = (unsigned short*)(wsf + 666128);  // 983040 us = 491520 f
  float* t2e     = wsf + 1157648;               // 491520
  float* h1      = wsf + 1649168;               // 122880
  float* params  = wsf + 1772048;               // 61440
  float* params_s= wsf + 1833488;               // 61440
  float* feat_s  = wsf + 1894928;               // 491520
  float* tch     = wsf + 2386448;               // 245760
  float* lev     = wsf + 2632208;               // 491520
  unsigned short* levb = (unsigned short*)(wsf + 3123728);  // 491520 us = 245760 f
  float* zbuf    = wsf + 3369488;               // 7680
  int*   rank    = (int*)(wsf + 3377168);       // 7680
  int*   ord     = (int*)(wsf + 3384848);       // 7680
  // end @ 3,392,528 f = 13.57 MB < 16.6 MB proven

  // dtype sniff, then one merged prep launch (cvt + bf16 operand builds)
  sniff_k<<<1, 256, 0, stream>>>((const unsigned short*)fl_w1, flag);
  prep_k<<<5098, 256, 0, stream>>>(flag,
      disp, invK, Km, rot_w2, rot_b2, scl_w2, scl_b2, opa_w2, opa_b2,
      rot_b1, scl_b1, opa_b1, fl_b1, fl_b2, fr_b,
      rot_w1, scl_w1, opa_w1, fl_w1, fl_w2, fr_w, init_feature,
      dispf, smallf, biasf, wp_h1, a_fl1, a_fl2, a_fr, xb);

  // heads first conv (VALU, flag-driven) -> h1
  head_conv_k<<<dim3(5, 48), 256, 0, stream>>>(init_feature, wp_h1, biasf, flag, h1);
  // fl1: 128->128 reflect MFMA GEMM; elu(+b1) -> bf16 t1b
  gemm_conv_k<1><<<dim3(60, 2), 256, 0, stream>>>(a_fl1, xb, biasf + 16, t1b, flag, 1152);
  // fl2: 128->64 reflect MFMA GEMM; elu(+b2) -> f32 t2e
  gemm_conv_k<0><<<dim3(60, 1), 256, 0, stream>>>(a_fl2, t1b, biasf + 144, t2e, flag, 1152);
  // heads second conv + gaussian prep
  head2_prep_k<<<60, 128, 0, stream>>>(h1, smallf, dispf, params, zbuf, rank);
  // stable argsort + gather (+ zero lev)
  rank_count_k<<<dim3(30, 8), 256, 0, stream>>>(zbuf, rank);
  scatter_k<<<30, 256, 0, stream>>>(rank, ord);
  gather_k<<<(NP * 64) / 256, 256, 0, stream>>>(ord, params, t2e, params_s, feat_s, lev);
  // two-pass raster
  alpha_k<<<dim3(NP / 256, NCHUNK), 256, 0, stream>>>(params_s, tch);
  raster_k<<<dim3(NP / 128, NCHUNK), 128, 0, stream>>>(params_s, feat_s, tch, lev);
  // final conv: 64->128 reflect MFMA GEMM; elu(+b_fr) -> d_out (dtype per flag)
  cvt_lev_k<<<1920, 256, 0, stream>>>(lev, levb);
  gemm_conv_k<2><<<dim3(60, 2), 256, 0, stream>>>(a_fr, levb, biasf + 208, d_out, flag, 576);
}